// Round 5
// baseline (17.140 us; speedup 1.0000x reference)
//
#include <hip/hip_runtime.h>

// Unit-stride loads: lane i loads float4 at base+i -> each wave load is one
// contiguous 1KB segment. 4 lanes cooperate per token; quad shfl_xor reduce.
__global__ __launch_bounds__(256, 8) void qfc_kernel(
    const float* __restrict__ x,
    const float* __restrict__ theta,
    const float* __restrict__ w,
    const float* __restrict__ bias,
    float* __restrict__ out)
{
    const int lane = threadIdx.x & 63;
    const long wave = (long)blockIdx.x * 4 + (threadIdx.x >> 6);

    // Lane handles quarter (lane&3) of each token: 4 cos for setup, not 16.
    const int q4 = lane & 3;
    float4 th = reinterpret_cast<const float4*>(theta)[q4];
    float4 ww = reinterpret_cast<const float4*>(w)[q4];
    float c0 = __cosf(th.x) * ww.x;
    float c1 = __cosf(th.y) * ww.y;
    float c2 = __cosf(th.z) * ww.z;
    float c3 = __cosf(th.w) * ww.w;
    float bb = bias[0];

    // Wave chunk: 16 rounds x 64 float4 (1KB contiguous per round).
    const float4* xv = reinterpret_cast<const float4*>(x) + wave * 1024 + lane;
    float* outw = out + wave * 256;

    const int j = lane >> 2;            // token within round
    const bool writer = (q4 == 0);

#pragma unroll
    for (int g = 0; g < 4; ++g) {       // 4 groups of 4 rounds, loads batched
        float4 v[4];
#pragma unroll
        for (int r = 0; r < 4; ++r) v[r] = xv[(g * 4 + r) * 64];
#pragma unroll
        for (int r = 0; r < 4; ++r) {
            float s = __cosf(v[r].x) * c0 + __cosf(v[r].y) * c1
                    + __cosf(v[r].z) * c2 + __cosf(v[r].w) * c3;
            s += __shfl_xor(s, 1);      // quad_perm DPP, VALU-only
            s += __shfl_xor(s, 2);
            if (writer) outw[(g * 4 + r) * 16 + j] = s + bb;
        }
    }
}

extern "C" void kernel_launch(void* const* d_in, const int* in_sizes, int n_in,
                              void* d_out, int out_size, void* d_ws, size_t ws_size,
                              hipStream_t stream) {
    const float* x     = (const float*)d_in[0];  // [B, S, 16]
    const float* theta = (const float*)d_in[1];  // [16]
    const float* w     = (const float*)d_in[2];  // [1, 16]
    const float* bias  = (const float*)d_in[3];  // [1]
    float* out = (float*)d_out;                  // [B*S] flat

    // 1M tokens / 256 tokens-per-wave = 4096 waves = 1024 blocks x 256 thr.
    int waves = out_size / 256;
    int grid = waves / 4;
    qfc_kernel<<<grid, 256, 0, stream>>>(x, theta, w, bias, out);
}